// Round 2
// baseline (114.850 us; speedup 1.0000x reference)
//
#include <hip/hip_runtime.h>

#define H 1024
#define W 1024
#define TILE 32
#define HALO4 40   // TILE + 8 (luma halo, +-4)
#define HALO2 36   // TILE + 4 (weight/rgb halo, +-2)

__global__ __launch_bounds__(256, 4)
void kuwahara_kernel(const float* __restrict__ inp, float* __restrict__ out) {
    __shared__ float  s_lum[HALO4][HALO4];   // zero-padded luma
    __shared__ float2 s_rs [HALO4][HALO2];   // horizontal (sum, sum_sq) of luma
    __shared__ float4 s_vw [HALO2][HALO2];   // (r, g, b, k->weight), edge-replicated

    const int tid = threadIdx.x;
    const int n  = blockIdx.z;
    const int y0 = blockIdx.y * TILE;
    const int x0 = blockIdx.x * TILE;

    const float* __restrict__ pR = inp + ((size_t)(4*n + 0) << 20);
    const float* __restrict__ pG = inp + ((size_t)(4*n + 1) << 20);
    const float* __restrict__ pB = inp + ((size_t)(4*n + 2) << 20);
    const float* __restrict__ pK = inp + ((size_t)(4*n + 3) << 20);

    const int tx  = tid & 31;   // column within tile
    const int tg  = tid >> 5;   // row-group: owns rows 4*tg .. 4*tg+3
    const int gx  = x0 + tx;
    const int pr0 = tg << 2;

    // ---- per-pixel constants from k at this thread's 4 output pixels ----
    float kc[4], t1[4], t4[4], cb[4];
#pragma unroll
    for (int p = 0; p < 4; ++p) {
        kc[p] = pK[((y0 + pr0 + p) << 10) + gx];
        // t = exp(-invwidth/25), invwidth = 64*(1-k); spatial factor = t^(dx^2+dy^2)
        float t = __expf(-2.56f * (1.0f - kc[p]));
        t1[p] = t;
        t4[p] = (t * t) * (t * t);
        cb[p] = 16.0f + kc[p] * (0.001f - 16.0f);   // center boost
    }

    // ---- stage 1: halo load. luma zero-padded; rgbk edge-replicated ----
    for (int idx = tid; idx < HALO4 * HALO4; idx += 256) {
        int j  = idx / HALO4;
        int i  = idx - j * HALO4;
        int gy = y0 - 4 + j;
        int gc = x0 - 4 + i;
        bool in = ((unsigned)gy < (unsigned)H) & ((unsigned)gc < (unsigned)W);
        int cy = min(max(gy, 0), H - 1);
        int cx = min(max(gc, 0), W - 1);
        int off = (cy << 10) + cx;
        float r = pR[off], g = pG[off], b = pB[off], k = pK[off];
        float l = 0.2126f * r + 0.7152f * g + 0.0722f * b;
        s_lum[j][i] = in ? l : 0.0f;                 // zero pad (box filter)
        if (j >= 2 && j < HALO4 - 2 && i >= 2 && i < HALO4 - 2)
            s_vw[j - 2][i - 2] = make_float4(r, g, b, k);   // edge pad
    }
    __syncthreads();

    // ---- stage 2: horizontal 5-tap sums of luma and luma^2 ----
    for (int idx = tid; idx < HALO4 * HALO2; idx += 256) {
        int j  = idx / HALO2;
        int i2 = idx - j * HALO2;
        float l0 = s_lum[j][i2+0], l1 = s_lum[j][i2+1], l2 = s_lum[j][i2+2];
        float l3 = s_lum[j][i2+3], l4 = s_lum[j][i2+4];
        float s  = ((l0 + l1) + (l2 + l3)) + l4;
        float s2 = ((l0*l0 + l1*l1) + (l2*l2 + l3*l3)) + l4*l4;
        s_rs[j][i2] = make_float2(s, s2);
    }
    __syncthreads();

    // ---- stage 3: vertical sums at CLAMPED center -> variance -> weight ----
    for (int idx = tid; idx < HALO2 * HALO2; idx += 256) {
        int j2 = idx / HALO2;
        int i2 = idx - j2 * HALO2;
        int gyc = min(max(y0 - 2 + j2, 0), H - 1);   // clamped center of window
        int gxc = min(max(x0 - 2 + i2, 0), W - 1);
        int js  = gyc - y0 + 2;                      // s_rs row of window top
        int is  = gxc - x0 + 2;                      // s_rs col of window start
        float2 a = s_rs[js+0][is], b = s_rs[js+1][is], c = s_rs[js+2][is];
        float2 d = s_rs[js+3][is], e = s_rs[js+4][is];
        float mean = (((a.x + b.x) + (c.x + d.x)) + e.x) * 0.04f;
        float msq  = (((a.y + b.y) + (c.y + d.y)) + e.y) * 0.04f;
        float var  = fabsf(msq - mean * mean);
        float kk   = s_vw[j2][i2].w;                 // k stashed in stage 1
        s_vw[j2][i2].w = __expf(-var * 64.0f * kk);  // edge-padded weight
    }
    __syncthreads();

    // ---- stage 4: 25-tap filter; factorized row sums shared across 4 px ----
    float accR[4], accG[4], accB[4], accW[4];
    float ctrR[4], ctrG[4], ctrB[4];
#pragma unroll
    for (int p = 0; p < 4; ++p) { accR[p] = accG[p] = accB[p] = accW[p] = 0.f; }

#pragma unroll
    for (int r8 = 0; r8 < 8; ++r8) {
        const float4* row = &s_vw[pr0 + r8][tx];     // single base, imm offsets
        float4 a0 = row[0], a1 = row[1], a2 = row[2], a3 = row[3], a4 = row[4];
        // partial sums by |dx|: S0 (dx=0), S1 (|dx|=1), S2 (|dx|=2)
        float S0w = a2.w;
        float S0x = a2.w * a2.x, S0y = a2.w * a2.y, S0z = a2.w * a2.z;
        float S1w = a1.w + a3.w;
        float S1x = a1.w * a1.x + a3.w * a3.x;
        float S1y = a1.w * a1.y + a3.w * a3.y;
        float S1z = a1.w * a1.z + a3.w * a3.z;
        float S2w = a0.w + a4.w;
        float S2x = a0.w * a0.x + a4.w * a4.x;
        float S2y = a0.w * a0.y + a4.w * a4.y;
        float S2z = a0.w * a0.z + a4.w * a4.z;
#pragma unroll
        for (int p = 0; p < 4; ++p) {
            const int dy = r8 - 2 - p;               // compile-time after unroll
            if (dy < -2 || dy > 2) continue;
            const int ady = dy < 0 ? -dy : dy;
            float rw = S0w + t1[p] * S1w + t4[p] * S2w;
            float rx = S0x + t1[p] * S1x + t4[p] * S2x;
            float ry = S0y + t1[p] * S1y + t4[p] * S2y;
            float rz = S0z + t1[p] * S1z + t4[p] * S2z;
            if (ady == 0) {
                ctrR[p] = a2.x; ctrG[p] = a2.y; ctrB[p] = a2.z;
                accR[p] += rx; accG[p] += ry; accB[p] += rz; accW[p] += rw;
            } else {
                float rf = (ady == 1) ? t1[p] : t4[p];
                accR[p] += rf * rx; accG[p] += rf * ry;
                accB[p] += rf * rz; accW[p] += rf * rw;
            }
        }
    }

    float* __restrict__ oR = out + ((size_t)(3*n + 0) << 20);
    float* __restrict__ oG = out + ((size_t)(3*n + 1) << 20);
    float* __restrict__ oB = out + ((size_t)(3*n + 2) << 20);
#pragma unroll
    for (int p = 0; p < 4; ++p) {
        // fold in center boost
        accR[p] += cb[p] * ctrR[p];
        accG[p] += cb[p] * ctrG[p];
        accB[p] += cb[p] * ctrB[p];
        accW[p] += cb[p];
        float inv = __builtin_amdgcn_rcpf(accW[p]);
        int off = ((y0 + pr0 + p) << 10) + gx;
        oR[off] = ctrR[p] + kc[p] * (accR[p] * inv - ctrR[p]);
        oG[off] = ctrG[p] + kc[p] * (accG[p] * inv - ctrG[p]);
        oB[off] = ctrB[p] + kc[p] * (accB[p] * inv - ctrB[p]);
    }
}

extern "C" void kernel_launch(void* const* d_in, const int* in_sizes, int n_in,
                              void* d_out, int out_size, void* d_ws, size_t ws_size,
                              hipStream_t stream) {
    const float* inp = (const float*)d_in[0];
    float* out = (float*)d_out;
    dim3 grid(W / TILE, H / TILE, 4);
    hipLaunchKernelGGL(kuwahara_kernel, grid, dim3(256), 0, stream, inp, out);
}

// Round 3
// 60.476 us; speedup vs baseline: 1.8991x; 1.8991x over previous
//
#include <hip/hip_runtime.h>

#define H 1024
#define W 1024
#define TILE 32
#define HALO4 40   // TILE + 8 (luma halo, +-4)
#define HALO2 36   // TILE + 4 (weight/rgb halo, +-2)

__global__ __launch_bounds__(256)
void kuwahara_kernel(const float* __restrict__ inp, float* __restrict__ out) {
    __shared__ float  s_lum[HALO4][HALO4];   // zero-padded luma
    __shared__ float2 s_rs [HALO4][HALO2];   // horizontal (sum, sum_sq) of luma
    __shared__ float4 s_vw [HALO2][HALO2];   // (r, g, b, k->weight), edge-replicated

    const int tid = threadIdx.x;
    const int n  = blockIdx.z;
    const int y0 = blockIdx.y * TILE;
    const int x0 = blockIdx.x * TILE;

    const float* __restrict__ pR = inp + ((size_t)(4*n + 0) << 20);
    const float* __restrict__ pG = inp + ((size_t)(4*n + 1) << 20);
    const float* __restrict__ pB = inp + ((size_t)(4*n + 2) << 20);
    const float* __restrict__ pK = inp + ((size_t)(4*n + 3) << 20);

    const int tx  = tid & 31;   // column within tile
    const int tg  = tid >> 5;   // row-group: owns rows 4*tg .. 4*tg+3
    const int gx  = x0 + tx;
    const int pr0 = tg << 2;

    // ---- per-pixel constants from k at this thread's 4 output pixels ----
    float kc[4], t1[4], t4[4], cb[4];
#pragma unroll
    for (int p = 0; p < 4; ++p) {
        kc[p] = pK[((y0 + pr0 + p) << 10) + gx];
        // t = exp(-invwidth/25), invwidth = 64*(1-k); spatial factor = t^(dx^2+dy^2)
        float t = __expf(-2.56f * (1.0f - kc[p]));
        t1[p] = t;
        t4[p] = (t * t) * (t * t);
        cb[p] = 16.0f + kc[p] * (0.001f - 16.0f);   // center boost
    }

    // ---- stage 1: halo load. luma zero-padded; rgbk edge-replicated ----
    for (int idx = tid; idx < HALO4 * HALO4; idx += 256) {
        int j  = idx / HALO4;
        int i  = idx - j * HALO4;
        int gy = y0 - 4 + j;
        int gc = x0 - 4 + i;
        bool in = ((unsigned)gy < (unsigned)H) & ((unsigned)gc < (unsigned)W);
        int cy = min(max(gy, 0), H - 1);
        int cx = min(max(gc, 0), W - 1);
        int off = (cy << 10) + cx;
        float r = pR[off], g = pG[off], b = pB[off], k = pK[off];
        float l = 0.2126f * r + 0.7152f * g + 0.0722f * b;
        s_lum[j][i] = in ? l : 0.0f;                 // zero pad (box filter)
        if (j >= 2 && j < HALO4 - 2 && i >= 2 && i < HALO4 - 2)
            s_vw[j - 2][i - 2] = make_float4(r, g, b, k);   // edge pad
    }
    __syncthreads();

    // ---- stage 2: horizontal 5-tap sums of luma and luma^2 ----
    for (int idx = tid; idx < HALO4 * HALO2; idx += 256) {
        int j  = idx / HALO2;
        int i2 = idx - j * HALO2;
        float l0 = s_lum[j][i2+0], l1 = s_lum[j][i2+1], l2 = s_lum[j][i2+2];
        float l3 = s_lum[j][i2+3], l4 = s_lum[j][i2+4];
        float s  = ((l0 + l1) + (l2 + l3)) + l4;
        float s2 = ((l0*l0 + l1*l1) + (l2*l2 + l3*l3)) + l4*l4;
        s_rs[j][i2] = make_float2(s, s2);
    }
    __syncthreads();

    // ---- stage 3: vertical sums at CLAMPED center -> variance -> weight ----
    for (int idx = tid; idx < HALO2 * HALO2; idx += 256) {
        int j2 = idx / HALO2;
        int i2 = idx - j2 * HALO2;
        int gyc = min(max(y0 - 2 + j2, 0), H - 1);   // clamped center of window
        int gxc = min(max(x0 - 2 + i2, 0), W - 1);
        int js  = gyc - y0 + 2;                      // s_rs row of window top
        int is  = gxc - x0 + 2;                      // s_rs col of window start
        float2 a = s_rs[js+0][is], b = s_rs[js+1][is], c = s_rs[js+2][is];
        float2 d = s_rs[js+3][is], e = s_rs[js+4][is];
        float mean = (((a.x + b.x) + (c.x + d.x)) + e.x) * 0.04f;
        float msq  = (((a.y + b.y) + (c.y + d.y)) + e.y) * 0.04f;
        float var  = fabsf(msq - mean * mean);
        float kk   = s_vw[j2][i2].w;                 // k stashed in stage 1
        s_vw[j2][i2].w = __expf(-var * 64.0f * kk);  // edge-padded weight
    }
    __syncthreads();

    // ---- stage 4: 25-tap filter; factorized row sums shared across 4 px ----
    float accR[4], accG[4], accB[4], accW[4];
    float ctrR[4], ctrG[4], ctrB[4];
#pragma unroll
    for (int p = 0; p < 4; ++p) { accR[p] = accG[p] = accB[p] = accW[p] = 0.f; }

#pragma unroll
    for (int r8 = 0; r8 < 8; ++r8) {
        const float4* row = &s_vw[pr0 + r8][tx];     // single base, imm offsets
        float4 a0 = row[0], a1 = row[1], a2 = row[2], a3 = row[3], a4 = row[4];
        // partial sums by |dx|: S0 (dx=0), S1 (|dx|=1), S2 (|dx|=2)
        float S0w = a2.w;
        float S0x = a2.w * a2.x, S0y = a2.w * a2.y, S0z = a2.w * a2.z;
        float S1w = a1.w + a3.w;
        float S1x = a1.w * a1.x + a3.w * a3.x;
        float S1y = a1.w * a1.y + a3.w * a3.y;
        float S1z = a1.w * a1.z + a3.w * a3.z;
        float S2w = a0.w + a4.w;
        float S2x = a0.w * a0.x + a4.w * a4.x;
        float S2y = a0.w * a0.y + a4.w * a4.y;
        float S2z = a0.w * a0.z + a4.w * a4.z;
#pragma unroll
        for (int p = 0; p < 4; ++p) {
            const int dy = r8 - 2 - p;               // compile-time after unroll
            if (dy < -2 || dy > 2) continue;
            const int ady = dy < 0 ? -dy : dy;
            float rw = S0w + t1[p] * S1w + t4[p] * S2w;
            float rx = S0x + t1[p] * S1x + t4[p] * S2x;
            float ry = S0y + t1[p] * S1y + t4[p] * S2y;
            float rz = S0z + t1[p] * S1z + t4[p] * S2z;
            if (ady == 0) {
                ctrR[p] = a2.x; ctrG[p] = a2.y; ctrB[p] = a2.z;
                accR[p] += rx; accG[p] += ry; accB[p] += rz; accW[p] += rw;
            } else {
                float rf = (ady == 1) ? t1[p] : t4[p];
                accR[p] += rf * rx; accG[p] += rf * ry;
                accB[p] += rf * rz; accW[p] += rf * rw;
            }
        }
    }

    float* __restrict__ oR = out + ((size_t)(3*n + 0) << 20);
    float* __restrict__ oG = out + ((size_t)(3*n + 1) << 20);
    float* __restrict__ oB = out + ((size_t)(3*n + 2) << 20);
#pragma unroll
    for (int p = 0; p < 4; ++p) {
        // fold in center boost
        accR[p] += cb[p] * ctrR[p];
        accG[p] += cb[p] * ctrG[p];
        accB[p] += cb[p] * ctrB[p];
        accW[p] += cb[p];
        float inv = __builtin_amdgcn_rcpf(accW[p]);
        int off = ((y0 + pr0 + p) << 10) + gx;
        oR[off] = ctrR[p] + kc[p] * (accR[p] * inv - ctrR[p]);
        oG[off] = ctrG[p] + kc[p] * (accG[p] * inv - ctrG[p]);
        oB[off] = ctrB[p] + kc[p] * (accB[p] * inv - ctrB[p]);
    }
}

extern "C" void kernel_launch(void* const* d_in, const int* in_sizes, int n_in,
                              void* d_out, int out_size, void* d_ws, size_t ws_size,
                              hipStream_t stream) {
    const float* inp = (const float*)d_in[0];
    float* out = (float*)d_out;
    dim3 grid(W / TILE, H / TILE, 4);
    hipLaunchKernelGGL(kuwahara_kernel, grid, dim3(256), 0, stream, inp, out);
}

// Round 5
// 52.993 us; speedup vs baseline: 2.1673x; 1.1412x over previous
//
#include <hip/hip_runtime.h>

#define H 1024
#define W 1024
#define TILE 32
#define HALO4 40   // TILE + 8 (luma halo, +-4)
#define HALO2 36   // TILE + 4 (weight/rgb halo, +-2)

__global__ __launch_bounds__(256)
void kuwahara_kernel(const float* __restrict__ inp, float* __restrict__ out) {
    __shared__ float  s_lum[HALO4][HALO4];   // zero-padded luma
    __shared__ float  s_s  [HALO4][HALO2];   // horizontal 5-sum of luma
    __shared__ float  s_sq [HALO4][HALO2];   // horizontal 5-sum of luma^2
    __shared__ float4 s_vw [HALO2][HALO2];   // (r, g, b, k->weight), edge-replicated

    const int tid = threadIdx.x;
    const int n  = blockIdx.z;
    const int y0 = blockIdx.y * TILE;
    const int x0 = blockIdx.x * TILE;

    const float* __restrict__ pR = inp + ((size_t)(4*n + 0) << 20);
    const float* __restrict__ pG = inp + ((size_t)(4*n + 1) << 20);
    const float* __restrict__ pB = inp + ((size_t)(4*n + 2) << 20);
    const float* __restrict__ pK = inp + ((size_t)(4*n + 3) << 20);

    const int tx  = tid & 31;   // column within tile
    const int tg  = tid >> 5;   // row-group: owns rows 4*tg .. 4*tg+3
    const int gx  = x0 + tx;
    const int pr0 = tg << 2;

    // ---- per-pixel constants from k at this thread's 4 output pixels ----
    float kc[4], t1[4], t4[4], cb[4];
#pragma unroll
    for (int p = 0; p < 4; ++p) {
        kc[p] = pK[((y0 + pr0 + p) << 10) + gx];
        // t = exp(-invwidth/25), invwidth = 64*(1-k); spatial factor = t^(dx^2+dy^2)
        float t = __expf(-2.56f * (1.0f - kc[p]));
        t1[p] = t;
        t4[p] = (t * t) * (t * t);
        cb[p] = 16.0f + kc[p] * (0.001f - 16.0f);   // center boost
    }

    // ---- stage 1: float4-vectorized halo load ----
    // 400 tasks: j in [0,40), q in [0,10); each loads 4 consecutive pixels.
    for (int idx = tid; idx < HALO4 * 10; idx += 256) {
        int j  = idx / 10, q = idx - j * 10;
        int gy = y0 - 4 + j;
        int cy = min(max(gy, 0), H - 1);
        int gcs = x0 - 4 + (q << 2);
        const int base = cy << 10;
        float rr[4], gg[4], bb[4], kk[4];
        if (gcs >= 0 && gcs <= W - 4) {          // x-interior: vector loads
            float4 r4 = *(const float4*)(pR + base + gcs);
            float4 g4 = *(const float4*)(pG + base + gcs);
            float4 b4 = *(const float4*)(pB + base + gcs);
            float4 k4 = *(const float4*)(pK + base + gcs);
            rr[0]=r4.x; rr[1]=r4.y; rr[2]=r4.z; rr[3]=r4.w;
            gg[0]=g4.x; gg[1]=g4.y; gg[2]=g4.z; gg[3]=g4.w;
            bb[0]=b4.x; bb[1]=b4.y; bb[2]=b4.z; bb[3]=b4.w;
            kk[0]=k4.x; kk[1]=k4.y; kk[2]=k4.z; kk[3]=k4.w;
        } else {                                  // x-border: clamped scalar
#pragma unroll
            for (int e = 0; e < 4; ++e) {
                int cx = min(max(gcs + e, 0), W - 1);
                rr[e] = pR[base + cx]; gg[e] = pG[base + cx];
                bb[e] = pB[base + cx]; kk[e] = pK[base + cx];
            }
        }
        bool rowIn = ((unsigned)gy < (unsigned)H);
        float lv[4];
#pragma unroll
        for (int e = 0; e < 4; ++e) {
            bool colIn = ((unsigned)(gcs + e) < (unsigned)W);
            lv[e] = (rowIn && colIn)
                      ? fmaf(0.2126f, rr[e], fmaf(0.7152f, gg[e], 0.0722f * bb[e]))
                      : 0.0f;                    // zero pad (box filter), row AND col
        }
        *(float4*)&s_lum[j][q << 2] = make_float4(lv[0], lv[1], lv[2], lv[3]);
        if (j >= 2 && j < HALO4 - 2) {
#pragma unroll
            for (int e = 0; e < 4; ++e) {
                int iv = (q << 2) + e - 2;
                if (iv >= 0 && iv < HALO2)
                    s_vw[j - 2][iv] = make_float4(rr[e], gg[e], bb[e], kk[e]); // edge pad
            }
        }
    }
    __syncthreads();

    // ---- stage 2: horizontal sliding 5-sums, 4 outputs per task ----
    // 360 tasks: j in [0,40), q in [0,9)
    for (int idx = tid; idx < HALO4 * 9; idx += 256) {
        int j = idx / 9, q = idx - j * 9;
        int c = q << 2;
        float4 v0 = *(const float4*)&s_lum[j][c];
        float4 v1 = *(const float4*)&s_lum[j][c + 4];
        float l[8] = {v0.x, v0.y, v0.z, v0.w, v1.x, v1.y, v1.z, v1.w};
        float s0 = ((l[0] + l[1]) + (l[2] + l[3])) + l[4];
        float s1 = s0 - l[0] + l[5];
        float s2 = s1 - l[1] + l[6];
        float s3 = s2 - l[2] + l[7];
        float m[8];
#pragma unroll
        for (int e = 0; e < 8; ++e) m[e] = l[e] * l[e];
        float u0 = ((m[0] + m[1]) + (m[2] + m[3])) + m[4];
        float u1 = u0 - m[0] + m[5];
        float u2 = u1 - m[1] + m[6];
        float u3 = u2 - m[2] + m[7];
        *(float4*)&s_s [j][c] = make_float4(s0, s1, s2, s3);
        *(float4*)&s_sq[j][c] = make_float4(u0, u1, u2, u3);
    }
    __syncthreads();

    // ---- stage 3: vertical 5-sum at clamped center -> variance -> weight ----
    // 324 tasks: j2 in [0,36), q in [0,9)
    for (int idx = tid; idx < HALO2 * 9; idx += 256) {
        int j2 = idx / 9, q = idx - j2 * 9;
        int c  = q << 2;
        int gyc = min(max(y0 - 2 + j2, 0), H - 1);  // clamped window-row origin
        int js  = gyc - y0 + 2;
        int g0  = x0 - 2 + c;                       // unclamped center col of e=0
        float as[4], aq[4];
        if (g0 >= 0 && g0 + 3 <= W - 1) {           // cols interior: vector path
            float4 accs = make_float4(0.f, 0.f, 0.f, 0.f);
            float4 accq = make_float4(0.f, 0.f, 0.f, 0.f);
#pragma unroll
            for (int r = 0; r < 5; ++r) {
                float4 vs = *(const float4*)&s_s [js + r][c];
                float4 vq = *(const float4*)&s_sq[js + r][c];
                accs.x += vs.x; accs.y += vs.y; accs.z += vs.z; accs.w += vs.w;
                accq.x += vq.x; accq.y += vq.y; accq.z += vq.z; accq.w += vq.w;
            }
            as[0]=accs.x; as[1]=accs.y; as[2]=accs.z; as[3]=accs.w;
            aq[0]=accq.x; aq[1]=accq.y; aq[2]=accq.z; aq[3]=accq.w;
        } else {                                    // x-border: clamped scalar
#pragma unroll
            for (int e = 0; e < 4; ++e) {
                int is = min(max(g0 + e, 0), W - 1) - x0 + 2;
                float ss = 0.f, sq = 0.f;
#pragma unroll
                for (int r = 0; r < 5; ++r) { ss += s_s[js + r][is]; sq += s_sq[js + r][is]; }
                as[e] = ss; aq[e] = sq;
            }
        }
#pragma unroll
        for (int e = 0; e < 4; ++e) {
            float mean = as[e] * 0.04f;
            float msq  = aq[e] * 0.04f;
            float var  = fabsf(msq - mean * mean);
            float kv   = s_vw[j2][c + e].w;          // k stashed in stage 1
            s_vw[j2][c + e].w = __expf(-var * 64.0f * kv);
        }
    }
    __syncthreads();

    // ---- stage 4: 25-tap filter; factorized row sums shared across 4 px ----
    float accR[4], accG[4], accB[4], accW[4];
    float ctrR[4], ctrG[4], ctrB[4];
#pragma unroll
    for (int p = 0; p < 4; ++p) { accR[p] = accG[p] = accB[p] = accW[p] = 0.f; }

#pragma unroll
    for (int r8 = 0; r8 < 8; ++r8) {
        const float4* row = &s_vw[pr0 + r8][tx];     // single base, imm offsets
        float4 a0 = row[0], a1 = row[1], a2 = row[2], a3 = row[3], a4 = row[4];
        // partial sums by |dx|: S0 (dx=0), S1 (|dx|=1), S2 (|dx|=2)
        float S0w = a2.w;
        float S0x = a2.w * a2.x, S0y = a2.w * a2.y, S0z = a2.w * a2.z;
        float S1w = a1.w + a3.w;
        float S1x = a1.w * a1.x + a3.w * a3.x;
        float S1y = a1.w * a1.y + a3.w * a3.y;
        float S1z = a1.w * a1.z + a3.w * a3.z;
        float S2w = a0.w + a4.w;
        float S2x = a0.w * a0.x + a4.w * a4.x;
        float S2y = a0.w * a0.y + a4.w * a4.y;
        float S2z = a0.w * a0.z + a4.w * a4.z;
#pragma unroll
        for (int p = 0; p < 4; ++p) {
            const int dy = r8 - 2 - p;               // compile-time after unroll
            if (dy < -2 || dy > 2) continue;
            const int ady = dy < 0 ? -dy : dy;
            float rw = S0w + t1[p] * S1w + t4[p] * S2w;
            float rx = S0x + t1[p] * S1x + t4[p] * S2x;
            float ry = S0y + t1[p] * S1y + t4[p] * S2y;
            float rz = S0z + t1[p] * S1z + t4[p] * S2z;
            if (ady == 0) {
                ctrR[p] = a2.x; ctrG[p] = a2.y; ctrB[p] = a2.z;
                accR[p] += rx; accG[p] += ry; accB[p] += rz; accW[p] += rw;
            } else {
                float rf = (ady == 1) ? t1[p] : t4[p];
                accR[p] += rf * rx; accG[p] += rf * ry;
                accB[p] += rf * rz; accW[p] += rf * rw;
            }
        }
    }

    float* __restrict__ oR = out + ((size_t)(3*n + 0) << 20);
    float* __restrict__ oG = out + ((size_t)(3*n + 1) << 20);
    float* __restrict__ oB = out + ((size_t)(3*n + 2) << 20);
#pragma unroll
    for (int p = 0; p < 4; ++p) {
        // fold in center boost
        accR[p] += cb[p] * ctrR[p];
        accG[p] += cb[p] * ctrG[p];
        accB[p] += cb[p] * ctrB[p];
        accW[p] += cb[p];
        float inv = __builtin_amdgcn_rcpf(accW[p]);
        int off = ((y0 + pr0 + p) << 10) + gx;
        oR[off] = ctrR[p] + kc[p] * (accR[p] * inv - ctrR[p]);
        oG[off] = ctrG[p] + kc[p] * (accG[p] * inv - ctrG[p]);
        oB[off] = ctrB[p] + kc[p] * (accB[p] * inv - ctrB[p]);
    }
}

extern "C" void kernel_launch(void* const* d_in, const int* in_sizes, int n_in,
                              void* d_out, int out_size, void* d_ws, size_t ws_size,
                              hipStream_t stream) {
    const float* inp = (const float*)d_in[0];
    float* out = (float*)d_out;
    dim3 grid(W / TILE, H / TILE, 4);
    hipLaunchKernelGGL(kuwahara_kernel, grid, dim3(256), 0, stream, inp, out);
}